// Round 16
// baseline (74.913 us; speedup 1.0000x reference)
//
#include <hip/hip_runtime.h>

// SequentialSparsemax: (8, 16, 262144) f32.
// pass1: sparsemax over 16 instruments at every (b, t).
// pass2: sparsemax over each 64-sample frame per (b, inst).
//
// r11's packed-f16 tile pipeline (best measured: 46.0 us, VGPR 44, zero
// scratch) extended with per-wave memory-level parallelism: each wave
// processes TWO tiles (A = wid, B = wid+4096). B's 16 float4 loads are
// prefetched in two half-batches of 8 (32 VGPRs in flight max):
//   half-1 issued before sort64(A)  (~1700cy of compute >> ~900cy HBM),
//   half-2 issued after half-1 is packed, drained after phase-3 A.
// Register peak ~80 (w[32] + 8 in-flight float4 + Ah[0..3]+nt2) under a
// __launch_bounds__(256,5) = 102-reg budget (r12/r13 spilled at 64-reg
// budgets; this has headroom). LDS = r11's 24 KiB/WG; grid = 1024 WGs =
// exactly 4 WG/CU -> 16 waves/CU in ONE generation, no tail; half of all
// tiles get fully-hidden load latency.
// Per-tile math is r11-verbatim (absmax 0.0039 proven):
//   pass1: Ah[16][2] u32; packed OEMS-16 (v_pk_max/min) sorts both times
//          at once; tau in f32 via inline unpack.
//   pass2: w[32] packed (e,e+32); 480/543 OEMS-64 CEs are lo/hi pk pairs.
//   staging: xor-8 ds_swizzle partner exchange builds (t,t+32) dwords;
//          12-slot LDS, rounds {0..11},{12..15}; insts 0..3 recomputed
//          from Ah at phase 3.

#define T_DIM   262144
#define N_INST  16
#define CHUNK   256                   // time samples per wave-tile (4 frames)
#define NCHUNK  (T_DIM / CHUNK)       // 1024
#define WPB     4                     // waves per block
#define NSLOT   12                    // LDS slots per wave (12 x 128 dwords)
#define HALF    4096                  // tiles per half (2 tiles per wave)

// ---- packed-f16 micro-ops (u32 = 2 x f16) ----
__device__ __forceinline__ unsigned pk_max(unsigned a, unsigned b) {
  unsigned r; asm("v_pk_max_f16 %0, %1, %2" : "=v"(r) : "v"(a), "v"(b)); return r;
}
__device__ __forceinline__ unsigned pk_min(unsigned a, unsigned b) {
  unsigned r; asm("v_pk_min_f16 %0, %1, %2" : "=v"(r) : "v"(a), "v"(b)); return r;
}
__device__ __forceinline__ unsigned pk_add(unsigned a, unsigned b) {
  unsigned r; asm("v_pk_add_f16 %0, %1, %2" : "=v"(r) : "v"(a), "v"(b)); return r;
}
__device__ __forceinline__ unsigned f2h(float x) {   // low16 valid, RNE
  unsigned r; asm("v_cvt_f16_f32 %0, %1" : "=v"(r) : "v"(x)); return r;
}
__device__ __forceinline__ float h2f(unsigned x) {   // converts low16
  float r; asm("v_cvt_f32_f16 %0, %1" : "=v"(r) : "v"(x)); return r;
}
__device__ __forceinline__ unsigned hswap(unsigned x) { return (x >> 16) | (x << 16); }
__device__ __forceinline__ unsigned lh(unsigned lo, unsigned hi) {
  return (lo & 0xFFFFu) | (hi & 0xFFFF0000u);   // [lo.lo16, hi.hi16] -> v_bfi
}
__device__ __forceinline__ unsigned packh(unsigned lo, unsigned hi) {
  return (lo & 0xFFFFu) | (hi << 16);           // both low16-valid inputs
}

// ---- CE helpers ----
__device__ __forceinline__ unsigned ce_max(unsigned a, unsigned b) { return pk_max(a, b); }
__device__ __forceinline__ unsigned ce_min(unsigned a, unsigned b) { return pk_min(a, b); }

// Batcher odd-even mergesort, descending; all indices compile-time after
// unroll; each register half an independent problem.
template<typename T, int N>
__device__ __forceinline__ void sort_desc_oems(T (&a)[N]) {
#pragma unroll
  for (int p = 1; p < N; p <<= 1) {
#pragma unroll
    for (int k = p; k >= 1; k >>= 1) {
#pragma unroll
      for (int j = k & (p - 1); j + k < N; j += 2 * k) {
#pragma unroll
        for (int i = 0; i < k; ++i) {
          if (i + j + k < N && (i + j) / (2 * p) == (i + j + k) / (2 * p)) {
            const T x = a[i + j], y = a[i + j + k];
            a[i + j]     = ce_max(x, y);
            a[i + j + k] = ce_min(x, y);
          }
        }
      }
    }
  }
}

// OEMS-64 on (e, e+32) split-packing: reg r = [pos r, pos r+32].
__device__ __forceinline__ void sort64_packed(unsigned (&a)[32]) {
#pragma unroll
  for (int p = 1; p < 64; p <<= 1) {
#pragma unroll
    for (int k = p; k >= 1; k >>= 1) {
#pragma unroll
      for (int j = k & (p - 1); j + k < 64; j += 2 * k) {
#pragma unroll
        for (int i = 0; i < k; ++i) {
          const int x = i + j, y = i + j + k;
          if (y < 64 && (x / (2 * p)) == (y / (2 * p))) {
            if (y < 32) {
              const unsigned A = a[x], B = a[y];
              a[x] = pk_max(A, B); a[y] = pk_min(A, B);
            } else if (x < 32) {
              if (y == x + 32) {              // within-register: [max,min]
                const unsigned A = a[x], S = hswap(A);
                a[x] = lh(pk_max(A, S), pk_min(A, S));
              } else {                        // cross: x lo <-> (y-32) hi
                const int ry = y - 32;
                const unsigned A = a[x], B = a[ry], Bs = hswap(B);
                const unsigned M = pk_max(A, Bs), m = pk_min(A, Bs);
                a[x]  = lh(M, A);             // lo=max(A.lo,B.hi), hi kept
                a[ry] = lh(B, hswap(m));      // lo kept, hi=min(A.lo,B.hi)
              }
            }
          }
        }
      }
    }
  }
}

// lgkm-only fence: orders this wave's own-LDS ops without draining vmcnt
// (prefetch loads stay in flight). Disjoint per-wave slices => no barrier.
__device__ __forceinline__ void lds_fence() {
  asm volatile("s_waitcnt lgkmcnt(0)" ::: "memory");
  __builtin_amdgcn_sched_barrier(0);
}

__device__ __forceinline__ unsigned swz_xor8(unsigned x) {
  return (unsigned)__builtin_amdgcn_ds_swizzle((int)x, (8 << 10) | 0x1f);
}

// ---- r11 tile stages as forceinline helpers ----
__device__ __forceinline__ void pass1_tau(const unsigned (&Ah)[N_INST][2],
                                          unsigned (&nt2)[2]) {
#pragma unroll
  for (int p = 0; p < 2; ++p) {
    unsigned z[N_INST];
#pragma unroll
    for (int i = 0; i < N_INST; ++i) z[i] = Ah[i][p];
    sort_desc_oems<unsigned, N_INST>(z);
    float csl = 0.f, csh = 0.f, tl = -1e30f, th = -1e30f;
#pragma unroll
    for (int k = 0; k < N_INST; ++k) {
      csl += h2f(z[k]);       tl = fmaxf(tl, (csl - 1.f) * (1.f / (float)(k + 1)));
      csh += h2f(z[k] >> 16); th = fmaxf(th, (csh - 1.f) * (1.f / (float)(k + 1)));
    }
    nt2[p] = packh(f2h(tl), f2h(th)) ^ 0x80008000u;   // negate both halves
  }
}

__device__ __forceinline__ void stage_gather(unsigned* __restrict__ sp,
                                             const unsigned (&Ah)[N_INST][2],
                                             const unsigned (&nt2)[2],
                                             int f, int lt0, bool lol,
                                             int i2, int f2,
                                             unsigned (&w)[32]) {
#pragma unroll
  for (int g = 0; g < 2; ++g) {
    if (g > 0) lds_fence();            // WAR: round-0 reads done
    const int i_lo = (g == 0) ? 0 : 12, i_hi = (g == 0) ? 12 : 16;
#pragma unroll
    for (int i = 0; i < N_INST; ++i) {
      if (i < i_lo || i >= i_hi) continue;
      const unsigned y0 = pk_max(pk_add(Ah[i][0], nt2[0]), 0u);
      const unsigned y1 = pk_max(pk_add(Ah[i][1], nt2[1]), 0u);
      const unsigned p0 = swz_xor8(y0);   // partner lane (^8): times +32
      const unsigned p1 = swz_xor8(y1);
      if (lol) {
        uint4 d;
        d.x = packh(y0, p0);              // [t=lt0+0, t+32]
        d.y = lh(y0 >> 16, p0);           // [t=lt0+1, t+32]
        d.z = packh(y1, p1);              // [t=lt0+2, t+32]
        d.w = lh(y1 >> 16, p1);           // [t=lt0+3, t+32]
        const int s = (i < 12) ? i : (i - 12);
        const int pd = s * 128 + f * 32 + (lt0 ^ ((s & 7) << 2));
        *reinterpret_cast<uint4*>(&sp[pd]) = d;
      }
    }
    lds_fence();                        // RAW: writes visible
    const bool mine = (g == 0) ? (i2 < 12) : (i2 >= 12);
    if (mine) {
      const int s = (i2 < 12) ? i2 : (i2 - 12);
#pragma unroll
      for (int v = 0; v < 8; ++v) {
        const int pd = s * 128 + f2 * 32 + ((4 * v) ^ ((s & 7) << 2));
        const uint4 d = *reinterpret_cast<const uint4*>(&sp[pd]);
        w[4 * v + 0] = d.x; w[4 * v + 1] = d.y;
        w[4 * v + 2] = d.z; w[4 * v + 3] = d.w;
      }
    }
  }
}

__device__ __forceinline__ float tau2_of(unsigned (&w)[32]) {
  sort64_packed(w);
  float csl = 0.f, csh = 0.f, bl = -1e30f, bh = -1e30f;
#pragma unroll
  for (int r = 0; r < 32; ++r) {        // ranks 1..32 (lo halves)
    csl += h2f(w[r]);
    bl = fmaxf(bl, (csl - 1.f) * (1.f / (float)(r + 1)));
  }
  const float dh = csl - 1.f;           // hi chain offset (ILP)
#pragma unroll
  for (int r = 0; r < 32; ++r) {        // ranks 33..64 (hi halves)
    csh += h2f(w[r] >> 16);
    bh = fmaxf(bh, (csh + dh) * (1.f / (float)(r + 33)));
  }
  return fmaxf(bl, bh);
}

__device__ __forceinline__ void phase3(const unsigned* __restrict__ sp,
                                       const unsigned (&Ah)[N_INST][2],
                                       const unsigned (&nt2)[2],
                                       float best, float* __restrict__ out,
                                       size_t base, int f, int lt0,
                                       int slb, unsigned hsh) {
#pragma unroll
  for (int i = 0; i < N_INST; ++i) {
    const float taui = __int_as_float(__builtin_amdgcn_ds_bpermute(
        (slb | i) << 2, __float_as_int(best)));
    float y0, y1, y2, y3;
    if (i < 4) {                        // slots overwritten: recompute from Ah
      const unsigned a0 = pk_max(pk_add(Ah[i][0], nt2[0]), 0u);
      const unsigned a1 = pk_max(pk_add(Ah[i][1], nt2[1]), 0u);
      y0 = h2f(a0); y1 = h2f(a0 >> 16); y2 = h2f(a1); y3 = h2f(a1 >> 16);
    } else {
      const int s = (i < 12) ? i : (i - 12);
      const int pd = s * 128 + f * 32 + ((lt0 & 31) ^ ((s & 7) << 2));
      const uint4 d = *reinterpret_cast<const uint4*>(&sp[pd]);
      y0 = h2f(d.x >> hsh); y1 = h2f(d.y >> hsh);
      y2 = h2f(d.z >> hsh); y3 = h2f(d.w >> hsh);
    }
    float4 o;
    o.x = fmaxf(y0 - taui, 0.0f);
    o.y = fmaxf(y1 - taui, 0.0f);
    o.z = fmaxf(y2 - taui, 0.0f);
    o.w = fmaxf(y3 - taui, 0.0f);
    *reinterpret_cast<float4*>(out + base + (size_t)i * T_DIM) = o;
  }
}

__global__ __launch_bounds__(256, 5) void seq_sparsemax_kernel(
    const float* __restrict__ in, float* __restrict__ out) {
  __shared__ __align__(16) unsigned lds[WPB * NSLOT * 128];  // 24 KiB

  const int lane = threadIdx.x & 63;
  const int wave = threadIdx.x >> 6;
  unsigned* __restrict__ sp = &lds[wave * NSLOT * 128];

  const int wid = blockIdx.x * WPB + wave;     // 0..4095

  const int f    = lane >> 4;          // this lane's frame (of 4)
  const int lt0  = 4 * (lane & 15);    // local time in frame, 0..60
  const bool lol = (lane & 8) == 0;    // lt0 < 32 (owns packed-dword writes)
  const int i2   = lane & 15;          // this lane's pass-2 row: inst
  const int f2   = lane >> 4;          //                         frame
  const int slb  = lane & 48;          // row-owner lane base for bpermute
  const unsigned hsh = (lane & 8) ? 16u : 0u;

  const int tidA = wid, tidB = wid + HALF;
  const size_t baseA = (size_t)(tidA >> 10) * N_INST * T_DIM +
                       (size_t)(tidA & (NCHUNK - 1)) * CHUNK + 4 * lane;
  const size_t baseB = (size_t)(tidB >> 10) * N_INST * T_DIM +
                       (size_t)(tidB & (NCHUNK - 1)) * CHUNK + 4 * lane;

  // ---- tile A: load + pack ----
  unsigned AhA[N_INST][2];
#pragma unroll
  for (int i = 0; i < N_INST; ++i) {
    const float4 q = *reinterpret_cast<const float4*>(in + baseA + (size_t)i * T_DIM);
    AhA[i][0] = packh(f2h(q.x), f2h(q.y));
    AhA[i][1] = packh(f2h(q.z), f2h(q.w));
  }

  unsigned nt2A[2];
  pass1_tau(AhA, nt2A);

  // ---- prefetch B half-1 (insts 0..7): in flight across A's sort ----
  float4 Bq[8];
#pragma unroll
  for (int i = 0; i < 8; ++i)
    Bq[i] = *reinterpret_cast<const float4*>(in + baseB + (size_t)i * T_DIM);
  __builtin_amdgcn_sched_barrier(0);   // pin issue point (no sinking)

  unsigned wA[32];
  stage_gather(sp, AhA, nt2A, f, lt0, lol, i2, f2, wA);
  const float bestA = tau2_of(wA);
  __builtin_amdgcn_sched_barrier(0);

  // ---- pack B half-1 (drains its vmcnt here, latency covered by sort);
  //      then prefetch B half-2 (in flight across phase-3 A) ----
  unsigned Bh[N_INST][2];
#pragma unroll
  for (int i = 0; i < 8; ++i) {
    Bh[i][0] = packh(f2h(Bq[i].x), f2h(Bq[i].y));
    Bh[i][1] = packh(f2h(Bq[i].z), f2h(Bq[i].w));
  }
#pragma unroll
  for (int i = 0; i < 8; ++i)
    Bq[i] = *reinterpret_cast<const float4*>(in + baseB + (size_t)(i + 8) * T_DIM);
  __builtin_amdgcn_sched_barrier(0);   // pin issue point

  // ---- phase-3 A (stores tile A) ----
  phase3(sp, AhA, nt2A, bestA, out, baseA, f, lt0, slb, hsh);

  // ---- pack B half-2 ----
#pragma unroll
  for (int i = 0; i < 8; ++i) {
    Bh[i + 8][0] = packh(f2h(Bq[i].x), f2h(Bq[i].y));
    Bh[i + 8][1] = packh(f2h(Bq[i].z), f2h(Bq[i].w));
  }

  // ---- tile B: full r11 pipeline from registers ----
  unsigned nt2B[2];
  pass1_tau(Bh, nt2B);
  lds_fence();   // WAR: A's phase-3 LDS reads complete before B staging
  unsigned wB[32];
  stage_gather(sp, Bh, nt2B, f, lt0, lol, i2, f2, wB);
  const float bestB = tau2_of(wB);
  __builtin_amdgcn_sched_barrier(0);
  phase3(sp, Bh, nt2B, bestB, out, baseB, f, lt0, slb, hsh);
}

extern "C" void kernel_launch(void* const* d_in, const int* in_sizes, int n_in,
                              void* d_out, int out_size, void* d_ws, size_t ws_size,
                              hipStream_t stream) {
  const float* in = (const float*)d_in[0];
  float* out = (float*)d_out;
  const int grid = HALF / WPB;   // 1024 blocks = 4 WG/CU, one generation
  seq_sparsemax_kernel<<<grid, 64 * WPB, 0, stream>>>(in, out);
}

// Round 17
// 46.542 us; speedup vs baseline: 1.6096x; 1.6096x over previous
//
#include <hip/hip_runtime.h>

// SequentialSparsemax: (8, 16, 262144) f32.
// pass1: sparsemax over 16 instruments at every (b, t).
// pass2: sparsemax over each 64-sample frame per (b, inst).
//
// EXACT r11 (best measured: 46.0 us bench, VGPR 44, zero scratch,
// FETCH 65.7 / WRITE 131 MB) + s_setprio(1) around the pass-2 sort+tau
// (barrier-free phase-skewed waves -> attn-like setprio case, m191).
// r12-r16 post-mortems: every larger-live-set structure spills (allocator
// cliff at ~64 effective regs); occupancy ~40% is structural. This is the
// empirical optimum design point.
//   pass1: Ah[16][2] u32 (2 times/reg); packed OEMS-16 (v_pk_max/min)
//          sorts both times at once; tau in f32 via inline unpack.
//   pass2: w[32] packed (e,e+32): 480/543 OEMS-64 CEs are lo/hi pairs;
//          32 within-reg + 31 cross CEs use merge forms.
//   staging: xor-8 ds_swizzle partner exchange builds (t,t+32) dwords;
//          12-slot LDS (6 KiB/wave), rounds {0..11}, {12..15}; insts 0..3
//          recomputed from Ah at phase 3 (proven liveness, no spill).

#define T_DIM   262144
#define N_INST  16
#define B_DIM   8
#define CHUNK   256                   // time samples per wave-tile (4 frames)
#define NCHUNK  (T_DIM / CHUNK)       // 1024
#define WPB     4                     // independent waves per block
#define NSLOT   12                    // LDS slots per wave (12 x 128 dwords)

// ---- packed-f16 micro-ops (u32 = 2 x f16) ----
__device__ __forceinline__ unsigned pk_max(unsigned a, unsigned b) {
  unsigned r; asm("v_pk_max_f16 %0, %1, %2" : "=v"(r) : "v"(a), "v"(b)); return r;
}
__device__ __forceinline__ unsigned pk_min(unsigned a, unsigned b) {
  unsigned r; asm("v_pk_min_f16 %0, %1, %2" : "=v"(r) : "v"(a), "v"(b)); return r;
}
__device__ __forceinline__ unsigned pk_add(unsigned a, unsigned b) {
  unsigned r; asm("v_pk_add_f16 %0, %1, %2" : "=v"(r) : "v"(a), "v"(b)); return r;
}
__device__ __forceinline__ unsigned f2h(float x) {   // low16 valid, RNE
  unsigned r; asm("v_cvt_f16_f32 %0, %1" : "=v"(r) : "v"(x)); return r;
}
__device__ __forceinline__ float h2f(unsigned x) {   // converts low16
  float r; asm("v_cvt_f32_f16 %0, %1" : "=v"(r) : "v"(x)); return r;
}
__device__ __forceinline__ unsigned hswap(unsigned x) { return (x >> 16) | (x << 16); }
__device__ __forceinline__ unsigned lh(unsigned lo, unsigned hi) {
  return (lo & 0xFFFFu) | (hi & 0xFFFF0000u);   // [lo.lo16, hi.hi16] -> v_bfi
}
__device__ __forceinline__ unsigned packh(unsigned lo, unsigned hi) {
  return (lo & 0xFFFFu) | (hi << 16);           // both low16-valid inputs
}

// ---- CE helpers: float (scalar) and unsigned (packed f16 pair) ----
__device__ __forceinline__ float    ce_max(float a, float b)       { return fmaxf(a, b); }
__device__ __forceinline__ float    ce_min(float a, float b)       { return fminf(a, b); }
__device__ __forceinline__ unsigned ce_max(unsigned a, unsigned b) { return pk_max(a, b); }
__device__ __forceinline__ unsigned ce_min(unsigned a, unsigned b) { return pk_min(a, b); }

// Batcher odd-even mergesort, descending (max to lower index); all indices
// compile-time after unroll. For T=unsigned each register half is an
// independent problem (packed SIMD sort).
template<typename T, int N>
__device__ __forceinline__ void sort_desc_oems(T (&a)[N]) {
#pragma unroll
  for (int p = 1; p < N; p <<= 1) {
#pragma unroll
    for (int k = p; k >= 1; k >>= 1) {
#pragma unroll
      for (int j = k & (p - 1); j + k < N; j += 2 * k) {
#pragma unroll
        for (int i = 0; i < k; ++i) {
          if (i + j + k < N && (i + j) / (2 * p) == (i + j + k) / (2 * p)) {
            const T x = a[i + j], y = a[i + j + k];
            a[i + j]     = ce_max(x, y);
            a[i + j + k] = ce_min(x, y);
          }
        }
      }
    }
  }
}

// OEMS-64 on (e, e+32) split-packing: reg r = [pos r, pos r+32].
// CE classes: both<32 -> plain pk pair (hi companion provably in network);
// y==x+32 -> within-register; x<32<=y -> cross (reg x lo <-> reg y-32 hi).
__device__ __forceinline__ void sort64_packed(unsigned (&a)[32]) {
#pragma unroll
  for (int p = 1; p < 64; p <<= 1) {
#pragma unroll
    for (int k = p; k >= 1; k >>= 1) {
#pragma unroll
      for (int j = k & (p - 1); j + k < 64; j += 2 * k) {
#pragma unroll
        for (int i = 0; i < k; ++i) {
          const int x = i + j, y = i + j + k;
          if (y < 64 && (x / (2 * p)) == (y / (2 * p))) {
            if (y < 32) {
              const unsigned A = a[x], B = a[y];
              a[x] = pk_max(A, B); a[y] = pk_min(A, B);
            } else if (x < 32) {
              if (y == x + 32) {              // within-register: [max,min]
                const unsigned A = a[x], S = hswap(A);
                a[x] = lh(pk_max(A, S), pk_min(A, S));
              } else {                        // cross: x lo <-> (y-32) hi
                const int ry = y - 32;
                const unsigned A = a[x], B = a[ry], Bs = hswap(B);
                const unsigned M = pk_max(A, Bs), m = pk_min(A, Bs);
                a[x]  = lh(M, A);             // lo=max(A.lo,B.hi), hi kept
                a[ry] = lh(B, hswap(m));      // lo kept, hi=min(A.lo,B.hi)
              }
            }
          }
        }
      }
    }
  }
}

// lgkm-only fence: orders this wave's own-LDS ops without draining vmcnt.
// Waves in the block use disjoint LDS slices => no s_barrier.
__device__ __forceinline__ void lds_fence() {
  asm volatile("s_waitcnt lgkmcnt(0)" ::: "memory");
  __builtin_amdgcn_sched_barrier(0);
}

__device__ __forceinline__ unsigned swz_xor8(unsigned x) {
  return (unsigned)__builtin_amdgcn_ds_swizzle((int)x, (8 << 10) | 0x1f);
}

__global__ __launch_bounds__(256, 8) void seq_sparsemax_kernel(
    const float* __restrict__ in, float* __restrict__ out) {
  __shared__ __align__(16) unsigned lds[WPB * NSLOT * 128];  // 24 KiB

  const int lane = threadIdx.x & 63;
  const int wave = threadIdx.x >> 6;
  unsigned* __restrict__ sp = &lds[wave * NSLOT * 128];

  const int tid   = blockIdx.x * WPB + wave;   // tile index 0..8191
  const int b     = tid >> 10;
  const int chunk = tid & (NCHUNK - 1);
  const size_t base = (size_t)b * N_INST * T_DIM + (size_t)chunk * CHUNK + 4 * lane;

  const int f    = lane >> 4;          // this lane's frame (of 4)
  const int lt0  = 4 * (lane & 15);    // local time in frame, 0..60
  const bool lol = (lane & 8) == 0;    // lt0 < 32 (owns packed-dword writes)

  // ---- load float4, convert to packed f16: Ah[i] = [(t0,t1),(t2,t3)] ----
  unsigned Ah[N_INST][2];
#pragma unroll
  for (int i = 0; i < N_INST; ++i) {
    const float4 q = *reinterpret_cast<const float4*>(in + base + (size_t)i * T_DIM);
    Ah[i][0] = packh(f2h(q.x), f2h(q.y));
    Ah[i][1] = packh(f2h(q.z), f2h(q.w));
  }

  // ---- pass 1: packed OEMS-16 sorts both times of a pair at once ----
  unsigned nt2[2];   // packed negated taus, [-tau_even, -tau_odd]
#pragma unroll
  for (int p = 0; p < 2; ++p) {
    unsigned z[N_INST];
#pragma unroll
    for (int i = 0; i < N_INST; ++i) z[i] = Ah[i][p];
    sort_desc_oems<unsigned, N_INST>(z);
    float csl = 0.f, csh = 0.f, tl = -1e30f, th = -1e30f;
#pragma unroll
    for (int k = 0; k < N_INST; ++k) {
      csl += h2f(z[k]);       tl = fmaxf(tl, (csl - 1.f) * (1.f / (float)(k + 1)));
      csh += h2f(z[k] >> 16); th = fmaxf(th, (csh - 1.f) * (1.f / (float)(k + 1)));
    }
    nt2[p] = packh(f2h(tl), f2h(th)) ^ 0x80008000u;   // negate both halves
  }

  const unsigned zz = 0u;  // Y(i,p) = pk_max(Ah + (-tau), 0)

  // ---- staging + gather, 2 rounds (12-slot LDS, overwrite scheme) ----
  // logical dword d of (slot s, frame fr) holds times (d, d+32) of the row;
  // physical dword = s*128 + fr*32 + (d ^ ((s&7)<<2)).
  const int i2 = lane & 15;            // this lane's pass-2 row: inst
  const int f2 = lane >> 4;            //                         frame
  unsigned w[32];

#pragma unroll
  for (int g = 0; g < 2; ++g) {
    if (g > 0) lds_fence();            // WAR: round-0 reads done
    const int i_lo = (g == 0) ? 0 : 12, i_hi = (g == 0) ? 12 : 16;
#pragma unroll
    for (int i = 0; i < N_INST; ++i) {
      if (i < i_lo || i >= i_hi) continue;
      const unsigned y0 = pk_max(pk_add(Ah[i][0], nt2[0]), zz);
      const unsigned y1 = pk_max(pk_add(Ah[i][1], nt2[1]), zz);
      const unsigned p0 = swz_xor8(y0);   // partner lane (^8): times +32
      const unsigned p1 = swz_xor8(y1);
      if (lol) {
        uint4 d;
        d.x = packh(y0, p0);              // [t=lt0+0, t+32]
        d.y = lh(y0 >> 16, p0);           // [t=lt0+1, t+32]
        d.z = packh(y1, p1);              // [t=lt0+2, t+32]
        d.w = lh(y1 >> 16, p1);           // [t=lt0+3, t+32]
        const int s = (i < 12) ? i : (i - 12);
        const int pd = s * 128 + f * 32 + (lt0 ^ ((s & 7) << 2));
        *reinterpret_cast<uint4*>(&sp[pd]) = d;
      }
    }
    lds_fence();                        // RAW: writes visible
    const bool mine = (g == 0) ? (i2 < 12) : (i2 >= 12);
    if (mine) {
      const int s = (i2 < 12) ? i2 : (i2 - 12);
#pragma unroll
      for (int v = 0; v < 8; ++v) {
        const int pd = s * 128 + f2 * 32 + ((4 * v) ^ ((s & 7) << 2));
        const uint4 d = *reinterpret_cast<const uint4*>(&sp[pd]);
        w[4 * v + 0] = d.x; w[4 * v + 1] = d.y;
        w[4 * v + 2] = d.z; w[4 * v + 3] = d.w;
      }
    }
  }

  // ---- pass 2: packed sort of this lane's 64-row, then tau (f32) ----
  // setprio(1): waves here are barrier-free and phase-skewed; prioritize
  // the pure-VALU sort so these waves re-enter their memory phase sooner.
  __builtin_amdgcn_s_setprio(1);
  sort64_packed(w);
  float cs = 0.f, best = -1e30f;
#pragma unroll
  for (int r = 0; r < 32; ++r) {        // ranks 1..32 (lo halves)
    cs += h2f(w[r]);
    best = fmaxf(best, (cs - 1.f) * (1.f / (float)(r + 1)));
  }
#pragma unroll
  for (int r = 0; r < 32; ++r) {        // ranks 33..64 (hi halves)
    cs += h2f(w[r] >> 16);
    best = fmaxf(best, (cs - 1.f) * (1.f / (float)(r + 33)));
  }
  __builtin_amdgcn_s_setprio(0);
  __builtin_amdgcn_sched_barrier(0);    // don't hoist phase 3 into the sort

  // ---- phase 3: pull row-taus; Y from LDS (i>=4) or recompute (i<4) ----
  const int slb = lane & 48;            // (lane>>4)*16: row-owner lane base
  const unsigned hsh = (lane & 8) ? 16u : 0u;   // my half in packed dwords
#pragma unroll
  for (int i = 0; i < N_INST; ++i) {
    const float taui = __int_as_float(__builtin_amdgcn_ds_bpermute(
        (slb | i) << 2, __float_as_int(best)));
    float y0, y1, y2, y3;
    if (i < 4) {                        // slots overwritten: recompute from Ah
      const unsigned a0 = pk_max(pk_add(Ah[i][0], nt2[0]), zz);
      const unsigned a1 = pk_max(pk_add(Ah[i][1], nt2[1]), zz);
      y0 = h2f(a0); y1 = h2f(a0 >> 16); y2 = h2f(a1); y3 = h2f(a1 >> 16);
    } else {
      const int s = (i < 12) ? i : (i - 12);
      const int pd = s * 128 + f * 32 + ((lt0 & 31) ^ ((s & 7) << 2));
      const uint4 d = *reinterpret_cast<const uint4*>(&sp[pd]);
      y0 = h2f(d.x >> hsh); y1 = h2f(d.y >> hsh);
      y2 = h2f(d.z >> hsh); y3 = h2f(d.w >> hsh);
    }
    float4 o;
    o.x = fmaxf(y0 - taui, 0.0f);
    o.y = fmaxf(y1 - taui, 0.0f);
    o.z = fmaxf(y2 - taui, 0.0f);
    o.w = fmaxf(y3 - taui, 0.0f);
    *reinterpret_cast<float4*>(out + base + (size_t)i * T_DIM) = o;
  }
}

extern "C" void kernel_launch(void* const* d_in, const int* in_sizes, int n_in,
                              void* d_out, int out_size, void* d_ws, size_t ws_size,
                              hipStream_t stream) {
  const float* in = (const float*)d_in[0];
  float* out = (float*)d_out;
  const int grid = B_DIM * NCHUNK / WPB;  // 2048 blocks x 4 waves
  seq_sparsemax_kernel<<<grid, 64 * WPB, 0, stream>>>(in, out);
}